// Round 6
// baseline (63.486 us; speedup 1.0000x reference)
//
#include <hip/hip_runtime.h>

// out[b,t,h,f] = in[b,t,f] * w[f,h] + bias[f,h]
// B=32 T=512 F=64 H=64. Output (B,T,H,F) fp32 = 256 MiB -> HBM-write-bound.
//
// Round-6 structure: flat sweep (round 5) + ALL inputs staged in LDS so the
// hot loop has ZERO vmcnt consumers (ds_read waits on lgkmcnt only). Stores
// free-run like fillBufferAligned's: no load-data wait ever drains the store
// queue (vmcnt retires in issue order, so a global-load wait would force all
// prior stores to ack -- that was round 5's suspected limiter).

constexpr int Fdim = 64;
constexpr int Hdim = 64;
constexpr int BLOCK = 256;
constexpr int GRID = 1024;   // 4 blocks/CU; 64 hot-loop iterations
constexpr int ITERS = 64;    // (B*T*H*F) / (GRID*BLOCK*4)

typedef float floatx4 __attribute__((ext_vector_type(4)));

__global__ __launch_bounds__(BLOCK) void embed_mad_kernel(
    const float* __restrict__ in,    // [B*T, F]
    const float* __restrict__ w,     // [F, H]
    const float* __restrict__ bias,  // [F, H]
    float* __restrict__ out)         // [B*T, H, F]
{
    __shared__ float s[ITERS * Fdim];   // 16 KiB, reused 3x in prologue
    const int tid = threadIdx.x;

    const int gtid = blockIdx.x * BLOCK + tid;
    const int o0 = gtid * 4;           // flat float index of this thread's float4
    const int f4 = o0 & 63;            // feature offset (invariant across iters)
    const int h  = (o0 >> 6) & 63;     // hidden index  (invariant across iters)
    const int rowbase = o0 >> 12;      // = blockIdx.x >> 2 (4 blocks per row)

    // --- phase 1: w transposed through LDS -> one float4 register ---
    for (int idx = tid; idx < Fdim * Hdim; idx += BLOCK) {
        int f = idx >> 6, hh = idx & 63;
        s[hh * Fdim + f] = w[idx];
    }
    __syncthreads();
    const floatx4 wv = *reinterpret_cast<const floatx4*>(&s[h * Fdim + f4]);
    __syncthreads();

    // --- phase 2: bias transposed through LDS -> one float4 register ---
    for (int idx = tid; idx < Fdim * Hdim; idx += BLOCK) {
        int f = idx >> 6, hh = idx & 63;
        s[hh * Fdim + f] = bias[idx];
    }
    __syncthreads();
    const floatx4 bv = *reinterpret_cast<const floatx4*>(&s[h * Fdim + f4]);
    __syncthreads();

    // --- phase 3: stage this block's entire input slice (64 rows x 256 B) ---
    // Row for iteration it: rowbase + it*256. 16-lane groups load one
    // contiguous 256 B row each -> coalesced.
    for (int k = tid; k < ITERS * 16; k += BLOCK) {
        int it = k >> 4, fi = k & 15;
        reinterpret_cast<floatx4*>(s)[k] =
            reinterpret_cast<const floatx4*>(in + (size_t)(rowbase + it * 256) * Fdim)[fi];
    }
    __syncthreads();

    // --- hot loop: ds_read_b128 + 4 FMA + wave-contiguous 1 KiB store.
    // No global loads -> no vmcnt waits -> store stream never drained.
    constexpr int STEP = GRID * BLOCK * 4;   // 1,048,576 floats per sweep step
    float* op = out + o0;

#pragma unroll 8
    for (int it = 0; it < ITERS; ++it) {
        const floatx4 iv = *reinterpret_cast<const floatx4*>(&s[it * Fdim + f4]);
        floatx4 ov;
        ov.x = fmaf(iv.x, wv.x, bv.x);
        ov.y = fmaf(iv.y, wv.y, bv.y);
        ov.z = fmaf(iv.z, wv.z, bv.z);
        ov.w = fmaf(iv.w, wv.w, bv.w);
        *reinterpret_cast<floatx4*>(op) = ov;
        op += STEP;
    }
}

extern "C" void kernel_launch(void* const* d_in, const int* in_sizes, int n_in,
                              void* d_out, int out_size, void* d_ws, size_t ws_size,
                              hipStream_t stream) {
    const float* in   = (const float*)d_in[0];  // (B,T,F) fp32
    const float* w    = (const float*)d_in[1];  // (F,H) fp32
    const float* bias = (const float*)d_in[2];  // (F,H) fp32
    float* out = (float*)d_out;                 // (B,T,H,F) fp32

    embed_mad_kernel<<<GRID, BLOCK, 0, stream>>>(in, w, bias, out);
}

// Round 7
// 54.744 us; speedup vs baseline: 1.1597x; 1.1597x over previous
//
#include <hip/hip_runtime.h>

// out[b,t,h,f] = in[b,t,f] * w[f,h] + bias[f,h]
// B=32 T=512 F=64 H=64. Output (B,T,H,F) fp32 = 256 MiB -> HBM-write-bound.
//
// Round-7: best structure (R5 flat sweep: each thread's (h,f4) invariant,
// w/b fragments in registers, hot loop = input load (64x reuse, cache-hit)
// + 4 FMA + wave-contiguous 1 KiB store). Prologue reduced to 8 direct
// register loads of the thread's w/b scalars -- no LDS, no barriers at all.
// Probe history: {nt,plain} x {slab,sweep} x {global-fed,LDS-fed} all land
// at 59-63 us (~4.5 TB/s effective); remaining gap to fillBuffer's 7 TB/s
// attributed to fixed dispatch overhead + read/write turnaround.

constexpr int Fdim = 64;
constexpr int Hdim = 64;
constexpr int BLOCK = 256;
constexpr int GRID = 1024;   // 4 blocks/CU; 64 hot-loop iterations; no tail

typedef float floatx4 __attribute__((ext_vector_type(4)));

__global__ __launch_bounds__(BLOCK) void embed_mad_kernel(
    const float* __restrict__ in,    // [B*T, F]
    const float* __restrict__ w,     // [F, H]
    const float* __restrict__ bias,  // [F, H]
    float* __restrict__ out,         // [B*T, H, F]
    int iters)
{
    const int gtid = blockIdx.x * BLOCK + threadIdx.x;
    const int o0 = gtid * 4;           // flat float index of this thread's float4
    const int f4 = o0 & 63;            // feature offset (invariant across iters)
    const int h  = (o0 >> 6) & 63;     // hidden index  (invariant across iters)
    const int row0 = o0 >> 12;         // starting output row

    // Direct register load of the 4 w and 4 bias scalars this thread ever
    // needs: w[f,h] at f*H + h. 8 independent dwords, one latency, L2-hit
    // after the first waves (w/b are 16 KiB each).
    floatx4 wv, bv;
    wv.x = w[(f4 + 0) * Hdim + h];
    wv.y = w[(f4 + 1) * Hdim + h];
    wv.z = w[(f4 + 2) * Hdim + h];
    wv.w = w[(f4 + 3) * Hdim + h];
    bv.x = bias[(f4 + 0) * Hdim + h];
    bv.y = bias[(f4 + 1) * Hdim + h];
    bv.z = bias[(f4 + 2) * Hdim + h];
    bv.w = bias[(f4 + 3) * Hdim + h];

    // Flat sweep: stride = GRID*BLOCK*4 floats = 1Mi floats = 256 rows, so
    // (h,f4) never changes; only the row advances.
    constexpr int STEP = GRID * BLOCK * 4;            // 1,048,576 floats
    constexpr int ROWSTEP = STEP / (Hdim * Fdim);     // 256 rows
    const float* ip = in + (size_t)row0 * Fdim + f4;
    float* op = out + o0;

#pragma unroll 4
    for (int it = 0; it < iters; ++it) {
        const floatx4 iv = *reinterpret_cast<const floatx4*>(ip);
        floatx4 ov;
        ov.x = fmaf(iv.x, wv.x, bv.x);
        ov.y = fmaf(iv.y, wv.y, bv.y);
        ov.z = fmaf(iv.z, wv.z, bv.z);
        ov.w = fmaf(iv.w, wv.w, bv.w);
        *reinterpret_cast<floatx4*>(op) = ov;   // wave-contiguous 1 KiB
        ip += ROWSTEP * Fdim;
        op += STEP;
    }
}

extern "C" void kernel_launch(void* const* d_in, const int* in_sizes, int n_in,
                              void* d_out, int out_size, void* d_ws, size_t ws_size,
                              hipStream_t stream) {
    const float* in   = (const float*)d_in[0];  // (B,T,F) fp32
    const float* w    = (const float*)d_in[1];  // (F,H) fp32
    const float* bias = (const float*)d_in[2];  // (F,H) fp32
    float* out = (float*)d_out;                 // (B,T,H,F) fp32

    const int iters = out_size / (GRID * BLOCK * 4);   // 64 for B*T=16384

    embed_mad_kernel<<<GRID, BLOCK, 0, stream>>>(in, w, bias, out, iters);
}

// Round 8
// 50.435 us; speedup vs baseline: 1.2588x; 1.0855x over previous
//
#include <hip/hip_runtime.h>

// out[b,t,h,f] = in[b,t,f] * w[f,h] + bias[f,h]
// B=32 T=512 F=64 H=64. Output (B,T,H,F) fp32 = 256 MiB -> HBM-write-bound.
//
// Round-8: 4 stores per input load. Each thread owns (f4..f4+3) x (hb..hb+3):
// one float4 input load feeds 4 output float4 stores (the 4x4 w/b fragment is
// held in 8 float4 registers, statically transposed inside the FMAs). Loads
// and stores share vmcnt and retire in issue order, so each wait-for-load
// drains all prior stores; quartering load frequency quarters those drains.
// Per iteration a block emits one full 16 KiB output row; grid sweeps rows.

constexpr int Fdim = 64;
constexpr int Hdim = 64;
constexpr int BLOCK = 256;
constexpr int GRID = 1024;   // rows/iter window = 1024 rows = 16 MiB front

typedef float floatx4 __attribute__((ext_vector_type(4)));

__global__ __launch_bounds__(BLOCK) void embed_mad_kernel(
    const float* __restrict__ in,    // [B*T, F]
    const float* __restrict__ w,     // [F, H]
    const float* __restrict__ bias,  // [F, H]
    float* __restrict__ out,         // [B*T, H, F]
    int iters)                       // rows / GRID = 16
{
    const int tid = threadIdx.x;
    const int f4 = (tid & 15) * 4;   // feature base (invariant)
    const int hb = (tid >> 4) * 4;   // hidden base  (invariant); block covers h 0..63

    // 4x4 (f,h) fragment of w and bias in registers.
    // wv[j] = w[f4+j][hb..hb+3] (16B aligned, contiguous along h).
    floatx4 wv[4], bf[4];
#pragma unroll
    for (int j = 0; j < 4; ++j) {
        wv[j] = *reinterpret_cast<const floatx4*>(w    + (f4 + j) * Hdim + hb);
        bf[j] = *reinterpret_cast<const floatx4*>(bias + (f4 + j) * Hdim + hb);
    }

    // Block b handles rows b, b+GRID, b+2*GRID, ... (16 MiB sweeping front).
    const int r0 = blockIdx.x;
    const float* ip = in + (size_t)r0 * Fdim + f4;
    float* op = out + (size_t)r0 * (Hdim * Fdim) + hb * Fdim + f4;

#pragma unroll 4
    for (int it = 0; it < iters; ++it) {
        const floatx4 iv = *reinterpret_cast<const floatx4*>(ip);
#pragma unroll
        for (int k = 0; k < 4; ++k) {
            floatx4 ov;
            ov.x = fmaf(iv.x, wv[0][k], bf[0][k]);   // f4+0, h=hb+k
            ov.y = fmaf(iv.y, wv[1][k], bf[1][k]);   // f4+1
            ov.z = fmaf(iv.z, wv[2][k], bf[2][k]);   // f4+2
            ov.w = fmaf(iv.w, wv[3][k], bf[3][k]);   // f4+3
            *reinterpret_cast<floatx4*>(op + k * Fdim) = ov;  // out[r, hb+k, f4]
        }
        ip += (size_t)GRID * Fdim;            // +1024 rows
        op += (size_t)GRID * (Hdim * Fdim);
    }
}

extern "C" void kernel_launch(void* const* d_in, const int* in_sizes, int n_in,
                              void* d_out, int out_size, void* d_ws, size_t ws_size,
                              hipStream_t stream) {
    const float* in   = (const float*)d_in[0];  // (B,T,F) fp32
    const float* w    = (const float*)d_in[1];  // (F,H) fp32
    const float* bias = (const float*)d_in[2];  // (F,H) fp32
    float* out = (float*)d_out;                 // (B,T,H,F) fp32

    const int rows = in_sizes[0] / Fdim;        // B*T = 16384
    const int iters = rows / GRID;              // 16

    embed_mad_kernel<<<GRID, BLOCK, 0, stream>>>(in, w, bias, out, iters);
}

// Round 9
// 50.264 us; speedup vs baseline: 1.2630x; 1.0034x over previous
//
#include <hip/hip_runtime.h>

// out[b,t,h,f] = in[b,t,f] * w[f,h] + bias[f,h]
// B=32 T=512 F=64 H=64. Output (B,T,H,F) fp32 = 256 MiB -> HBM-write-bound.
//
// Round-9: ALL loads before ALL stores. vmcnt retires in issue order, so a
// wait for load data forces every earlier-issued store to retire (drain).
// R7->R8 showed each 4x cut in drain frequency = -4.3 us. End state: each
// thread issues its 16 input loads (iv[16], statically indexed, full unroll)
// BEFORE its 64-store burst -> every load-consume wait has only YOUNGER
// stores outstanding -> zero store drains; store stream free-runs like
// fillBufferAligned (7 TB/s reference). Low tail occupancy from ~150 VGPR is
// fine: streaming saturates at ~10% occupancy (fillBuffer's own number).

constexpr int Fdim = 64;
constexpr int Hdim = 64;
constexpr int BLOCK = 256;
constexpr int GRID = 1024;
constexpr int ITERS = 16;    // 16384 rows / GRID

typedef float floatx4 __attribute__((ext_vector_type(4)));

__global__ __launch_bounds__(BLOCK) void embed_mad_kernel(
    const float* __restrict__ in,    // [B*T, F]
    const float* __restrict__ w,     // [F, H]
    const float* __restrict__ bias,  // [F, H]
    float* __restrict__ out)         // [B*T, H, F]
{
    const int tid = threadIdx.x;
    const int f4 = (tid & 15) * 4;   // feature base (invariant)
    const int hb = (tid >> 4) * 4;   // hidden base  (invariant)

    // 4x4 (f,h) register fragment of w and bias: wv[j] = w[f4+j][hb..hb+3].
    floatx4 wv[4], bf[4];
#pragma unroll
    for (int j = 0; j < 4; ++j) {
        wv[j] = *reinterpret_cast<const floatx4*>(w    + (f4 + j) * Hdim + hb);
        bf[j] = *reinterpret_cast<const floatx4*>(bias + (f4 + j) * Hdim + hb);
    }

    // Phase 1: issue ALL 16 input loads (independent, addresses static).
    const int r0 = blockIdx.x;       // block handles rows r0 + it*GRID
    const float* ip = in + (size_t)r0 * Fdim + f4;
    floatx4 ivs[ITERS];
#pragma unroll
    for (int it = 0; it < ITERS; ++it)
        ivs[it] = *reinterpret_cast<const floatx4*>(ip + (size_t)it * GRID * Fdim);

    // Phase 2: one uninterrupted 64-store burst (4 per row x 16 rows).
    float* op = out + (size_t)r0 * (Hdim * Fdim) + hb * Fdim + f4;
#pragma unroll
    for (int it = 0; it < ITERS; ++it) {
        const floatx4 iv = ivs[it];
#pragma unroll
        for (int k = 0; k < 4; ++k) {
            floatx4 ov;
            ov.x = fmaf(iv.x, wv[0][k], bf[0][k]);   // f4+0, h=hb+k
            ov.y = fmaf(iv.y, wv[1][k], bf[1][k]);   // f4+1
            ov.z = fmaf(iv.z, wv[2][k], bf[2][k]);   // f4+2
            ov.w = fmaf(iv.w, wv[3][k], bf[3][k]);   // f4+3
            *reinterpret_cast<floatx4*>(
                op + (size_t)it * GRID * (Hdim * Fdim) + k * Fdim) = ov;
        }
    }
}

extern "C" void kernel_launch(void* const* d_in, const int* in_sizes, int n_in,
                              void* d_out, int out_size, void* d_ws, size_t ws_size,
                              hipStream_t stream) {
    const float* in   = (const float*)d_in[0];  // (B,T,F) fp32
    const float* w    = (const float*)d_in[1];  // (F,H) fp32
    const float* bias = (const float*)d_in[2];  // (F,H) fp32
    float* out = (float*)d_out;                 // (B,T,H,F) fp32

    embed_mad_kernel<<<GRID, BLOCK, 0, stream>>>(in, w, bias, out);
}